// Round 2
// baseline (5081.139 us; speedup 1.0000x reference)
//
#include <hip/hip_runtime.h>

typedef unsigned int u32;
typedef unsigned short u16;
typedef unsigned long long u64;

#define NT 16384
#define NROW 262144            // 16 * 16384 rows total
#define LN7 1.9459101090932196f

__device__ __forceinline__ u32 f2bf(float f){
  u32 u = __float_as_uint(f);
  return (u + 0x7fffu + ((u >> 16) & 1u)) >> 16;   // RNE to bf16
}
__device__ __forceinline__ float bflo(u32 v){ return __uint_as_float(v << 16); }
__device__ __forceinline__ float bfhi(u32 v){ return __uint_as_float(v & 0xffff0000u); }

// ============================================================================
// k_pre: 256 blocks. Per row: LN(inputs), k->bf16, val->bf16, wi logit.
// Also: per-row logit + 1/||k|| to scratch, per-block LSE partials.
// ============================================================================
__global__ __launch_bounds__(1024) void k_pre(
    const float* __restrict__ inp,
    const float* __restrict__ Wk, const float* __restrict__ Wv,
    const float* __restrict__ lning, const float* __restrict__ lninb,
    const float* __restrict__ wiw, const float* __restrict__ wib,
    u16* __restrict__ knb, u16* __restrict__ valb,
    float* __restrict__ lgA, float* __restrict__ rnA,
    float* __restrict__ lsePart)
{
  const int tid = threadIdx.x, blk = blockIdx.x;
  const int batch = blk >> 4, chunk = blk & 15;
  const size_t row = ((size_t)batch << 14) | (size_t)((chunk << 10) | tid);

  __shared__ float red[16][2];
  __shared__ float sbm;

  float x[64];
  {
    const float4* x4 = (const float4*)(inp + row * 64);
    #pragma unroll
    for (int i = 0; i < 16; ++i){
      float4 t = x4[i];
      x[4*i] = t.x; x[4*i+1] = t.y; x[4*i+2] = t.z; x[4*i+3] = t.w;
    }
  }
  float mean = 0.f;
  #pragma unroll
  for (int i = 0; i < 64; ++i) mean += x[i];
  mean *= (1.f/64.f);
  float var = 0.f;
  #pragma unroll
  for (int i = 0; i < 64; ++i){ float d = x[i] - mean; var += d*d; }
  var *= (1.f/64.f);
  float rstd = rsqrtf(var + 1e-5f);
  float lg = wib[0];
  #pragma unroll
  for (int i = 0; i < 64; ++i){
    x[i] = (x[i] - mean) * rstd * lning[i] + lninb[i];
    lg += x[i] * wiw[i];
  }
  {
    u32 kp[32];
    float ss = 0.f;
    #pragma unroll 4
    for (int dp = 0; dp < 64; dp += 2){
      const float4* w0 = (const float4*)(Wk + dp*64);
      const float4* w1 = (const float4*)(Wk + dp*64 + 64);
      float a0 = 0.f, a1 = 0.f;
      #pragma unroll
      for (int q = 0; q < 16; ++q){
        float4 wa = w0[q], wb = w1[q];
        a0 += x[4*q]*wa.x + x[4*q+1]*wa.y + x[4*q+2]*wa.z + x[4*q+3]*wa.w;
        a1 += x[4*q]*wb.x + x[4*q+1]*wb.y + x[4*q+2]*wb.z + x[4*q+3]*wb.w;
      }
      ss += a0*a0 + a1*a1;
      kp[dp>>1] = f2bf(a0) | (f2bf(a1) << 16);
    }
    rnA[row] = 1.f / fmaxf(sqrtf(ss), 1e-12f);
    uint4* ko = (uint4*)(knb + row*64);
    #pragma unroll
    for (int i = 0; i < 8; ++i) ko[i] = ((uint4*)kp)[i];
    #pragma unroll 4
    for (int dp = 0; dp < 64; dp += 2){
      const float4* w0 = (const float4*)(Wv + dp*64);
      const float4* w1 = (const float4*)(Wv + dp*64 + 64);
      float a0 = 0.f, a1 = 0.f;
      #pragma unroll
      for (int q = 0; q < 16; ++q){
        float4 wa = w0[q], wb = w1[q];
        a0 += x[4*q]*wa.x + x[4*q+1]*wa.y + x[4*q+2]*wa.z + x[4*q+3]*wa.w;
        a1 += x[4*q]*wb.x + x[4*q+1]*wb.y + x[4*q+2]*wb.z + x[4*q+3]*wb.w;
      }
      kp[dp>>1] = f2bf(a0) | (f2bf(a1) << 16);
    }
    uint4* vo = (uint4*)(valb + row*64);
    #pragma unroll
    for (int i = 0; i < 8; ++i) vo[i] = ((uint4*)kp)[i];
  }
  lgA[row] = lg;

  // per-block LSE partials {max, sum(exp(lg-max))}
  float mx = lg;
  #pragma unroll
  for (int off = 32; off > 0; off >>= 1) mx = fmaxf(mx, __shfl_xor(mx, off, 64));
  if ((tid & 63) == 0) red[tid>>6][0] = mx;
  __syncthreads();
  if (tid == 0){
    float bm = red[0][0];
    for (int w = 1; w < 16; ++w) bm = fmaxf(bm, red[w][0]);
    sbm = bm;
  }
  __syncthreads();
  float se = __expf(lg - sbm);
  #pragma unroll
  for (int off = 32; off > 0; off >>= 1) se += __shfl_xor(se, off, 64);
  if ((tid & 63) == 0) red[tid>>6][1] = se;
  __syncthreads();
  if (tid == 0){
    float S = 0.f;
    for (int w = 0; w < 16; ++w) S += red[w][1];
    lsePart[blk*2 + 0] = sbm;
    lsePart[blk*2 + 1] = S;
  }
}

// ============================================================================
// k_mesh: 16 blocks, one batch per block, 16 rows per thread.
// All reductions block-local (LDS). No inter-block communication at all.
// Per-row state in L2-resident scratch: ec = exp(-c), rse (per fwd step), aR.
// pb gradient scratch overlays the attn output region (sequentially disjoint).
// ============================================================================
__global__ __launch_bounds__(1024) void k_mesh(
    const float* __restrict__ noise, const float* __restrict__ mu,
    const float* __restrict__ sigma, const float* __restrict__ Wq,
    const float* __restrict__ gwih, const float* __restrict__ gwhh,
    const float* __restrict__ gbih, const float* __restrict__ gbhh,
    const float* __restrict__ fc1w, const float* __restrict__ fc1b,
    const float* __restrict__ fc2w, const float* __restrict__ fc2b,
    const float* __restrict__ lnslg, const float* __restrict__ lnslb,
    const float* __restrict__ lnffg, const float* __restrict__ lnffb,
    const float* __restrict__ wsw, const float* __restrict__ wsb,
    const u16* __restrict__ knb, const u16* __restrict__ valb,
    const float* __restrict__ lgA, const float* __restrict__ rnA,
    const float* __restrict__ lsePart,
    float* __restrict__ ecA, float* __restrict__ rseA, float* __restrict__ aRA,
    float* out)
{
  const int tid = threadIdx.x;
  const int batch = blockIdx.x;

  __shared__ float Sl[7][64], Qn[7][64], Qt[7][64], Sst[7][64];
  __shared__ float Gx[7][192], Gh[7][192], H1[7][128];
  __shared__ float uacc[16][7][64];
  __shared__ float red[16][8];
  __shared__ float vh[6][8], logb[8], mxp[8];
  __shared__ float ev[8], vw[8], rt[8];
  __shared__ float sS[2];

  float* pbB = out + 7168 + (size_t)batch * 7 * NT;   // pb / attn region

  auto bred7 = [&](float* part){
    #pragma unroll
    for (int off = 32; off > 0; off >>= 1)
      #pragma unroll
      for (int s = 0; s < 7; ++s) part[s] += __shfl_xor(part[s], off, 64);
    if ((tid & 63) == 0){
      const int w = tid >> 6;
      #pragma unroll
      for (int s = 0; s < 7; ++s) red[w][s] = part[s];
    }
    __syncthreads();
  };

  // ---- init: combine batch LSE, per-row a = exp(la) ----
  if (tid == 0){
    float M = lsePart[batch*32];
    for (int w = 1; w < 16; ++w) M = fmaxf(M, lsePart[batch*32 + 2*w]);
    float S = 0.f;
    for (int w = 0; w < 16; ++w)
      S += __expf(lsePart[batch*32 + 2*w] - M) * lsePart[batch*32 + 2*w + 1];
    sS[0] = M + __logf(S);
  }
  __syncthreads();
  const float LSE = sS[0];
  for (int r = 0; r < 16; ++r){
    const size_t gr = ((size_t)batch << 14) | (size_t)((r << 10) | tid);
    aRA[gr] = __expf(lgA[gr] - LSE + LN7);
  }

  for (int it = 0; it < 3; ++it){
    // ---- prologue: slots -> sn, logb, q, qn ----
    if (tid < 448){
      float sl;
      if (it == 0){
        const int d = tid & 63;
        sl = mu[d] + (fabsf(sigma[d]) + 1e-8f) * noise[batch*448 + tid];
      } else sl = Sst[tid>>6][tid&63];
      Sl[tid>>6][tid&63] = sl;
    }
    if (tid < 8) vh[5][tid] = 0.f;
    __syncthreads();
    if (tid < 7){
      float m2 = 0.f;
      for (int d = 0; d < 64; ++d) m2 += Sl[tid][d];
      m2 *= (1.f/64.f);
      float v2 = 0.f;
      for (int d = 0; d < 64; ++d){ float dd = Sl[tid][d]-m2; v2 += dd*dd; }
      v2 *= (1.f/64.f);
      float rs2 = rsqrtf(v2 + 1e-5f);
      float lgq = wsb[0];
      for (int d = 0; d < 64; ++d){
        float s = (Sl[tid][d]-m2)*rs2*lnslg[d] + lnslb[d];
        Qt[tid][d] = s;
        lgq += s*wsw[d];
      }
      red[0][tid] = lgq;
    }
    __syncthreads();
    if (tid == 0){
      float mx = red[0][0];
      for (int s = 1; s < 7; ++s) mx = fmaxf(mx, red[0][s]);
      float sm = 0.f;
      for (int s = 0; s < 7; ++s) sm += __expf(red[0][s]-mx);
      float lse = mx + __logf(sm);
      for (int s = 0; s < 7; ++s) logb[s] = red[0][s] - lse + LN7;
    }
    __syncthreads();
    if (tid < 448){
      const int s = tid >> 6, d = tid & 63;
      const float* wr = Wq + d*64;
      float acc2 = 0.f;
      #pragma unroll
      for (int dd = 0; dd < 64; ++dd) acc2 += Qt[s][dd]*wr[dd];
      Sl[s][d] = acc2;
    }
    __syncthreads();
    if (tid < 7){
      float sq = 0.f;
      for (int d = 0; d < 64; ++d) sq += Sl[tid][d]*Sl[tid][d];
      red[1][tid] = 1.f/fmaxf(sqrtf(sq), 1e-12f);
    }
    __syncthreads();
    if (tid < 448) Qn[tid>>6][tid&63] = Sl[tid>>6][tid&63]*red[1][tid>>6];
    __syncthreads();

    // ---- C build -> ec = exp(-c) (per-thread-private rows) ----
    #pragma unroll 1
    for (int r = 0; r < 16; ++r){
      const int rw = (r << 10) | tid;
      const size_t gr = ((size_t)batch << 14) | (size_t)rw;
      float acc[7] = {0.f,0.f,0.f,0.f,0.f,0.f,0.f};
      const uint4* kr = (const uint4*)(knb + gr*64);
      #pragma unroll
      for (int q8 = 0; q8 < 8; ++q8){
        uint4 kv = kr[q8];
        float f0=bflo(kv.x), f1=bfhi(kv.x), f2=bflo(kv.y), f3=bfhi(kv.y);
        float f4=bflo(kv.z), f5=bfhi(kv.z), f6=bflo(kv.w), f7=bfhi(kv.w);
        const int d0 = q8*8;
        #pragma unroll
        for (int s = 0; s < 7; ++s){
          const float4 qa = *(const float4*)&Qn[s][d0];
          const float4 qb = *(const float4*)&Qn[s][d0+4];
          acc[s] += f0*qa.x + f1*qa.y + f2*qa.z + f3*qa.w
                  + f4*qb.x + f5*qb.y + f6*qb.z + f7*qb.w;
        }
      }
      const float rn_ = rnA[gr];
      #pragma unroll
      for (int s = 0; s < 7; ++s){
        float c = 1.f - rn_*acc[s];
        ecA[(size_t)s*NROW + gr] = __expf(-c);
      }
    }

    // ---- MESH: 4 grad passes (fwd5 + G + bwd5) + final fwd5 ----
    for (int m = 0; m < 5; ++m){
      if (tid == 0){                     // warm start + uniforms for t=1
        float mxn = vh[5][0];
        for (int s = 1; s < 7; ++s) mxn = fmaxf(mxn, vh[5][s]);
        for (int s = 0; s < 7; ++s){ vh[0][s] = vh[5][s]; ev[s] = __expf(vh[5][s] - mxn); }
        mxp[1] = mxn;
      }
      __syncthreads();

      for (int t = 1; t <= 5; ++t){
        float evr[7];
        #pragma unroll
        for (int s = 0; s < 7; ++s) evr[s] = ev[s];
        float t7[7] = {0.f,0.f,0.f,0.f,0.f,0.f,0.f};
        #pragma unroll 2
        for (int r = 0; r < 16; ++r){
          const int rw = (r << 10) | tid;
          const size_t gr = ((size_t)batch << 14) | (size_t)rw;
          float e[7];
          #pragma unroll
          for (int s = 0; s < 7; ++s) e[s] = ecA[(size_t)s*NROW + gr];
          const float aR = aRA[gr];
          float se = e[0]*evr[0];
          #pragma unroll
          for (int s = 1; s < 7; ++s) se += e[s]*evr[s];
          const float rse = 1.0f / se;
          rseA[(size_t)(t-1)*NROW + gr] = rse;
          const float w = aR * rse;
          #pragma unroll
          for (int s = 0; s < 7; ++s) t7[s] += w * e[s];
        }
        bred7(t7);
        if (tid == 0){
          for (int s = 0; s < 7; ++s){
            float T = red[0][s];
            for (int w = 1; w < 16; ++w) T += red[w][s];
            vh[t][s] = logb[s] + mxp[t] - __logf(T);
          }
          if (t < 5){
            float mxn = vh[t][0];
            for (int s = 1; s < 7; ++s) mxn = fmaxf(mxn, vh[t][s]);
            mxp[t+1] = mxn;
            for (int s = 0; s < 7; ++s) ev[s] = __expf(vh[t][s] - mxn);
          } else {
            for (int s = 0; s < 7; ++s) ev[s] = __expf(vh[5][s] - mxp[5]);   // EF
          }
        }
        __syncthreads();
      }
      if (m == 4) break;

      // ---- G phase: pb = G, reduce Sum(G) -> vb ----
      {
        float EF[7], vh5r[7];
        #pragma unroll
        for (int s = 0; s < 7; ++s){ EF[s] = ev[s]; vh5r[s] = vh[5][s]; }
        const float mx5 = mxp[5];
        float gs[7] = {0.f,0.f,0.f,0.f,0.f,0.f,0.f};
        #pragma unroll 1
        for (int r = 0; r < 16; ++r){
          const int rw = (r << 10) | tid;
          const size_t gr = ((size_t)batch << 14) | (size_t)rw;
          float e[7];
          #pragma unroll
          for (int s = 0; s < 7; ++s) e[s] = ecA[(size_t)s*NROW + gr];
          const float aR = aRA[gr];
          const float rse5 = rseA[(size_t)4*NROW + gr];
          const float la = lgA[gr] - LSE + LN7;
          const float q = aR * rse5;
          const float base = la - mx5 + __logf(rse5);
          #pragma unroll
          for (int s = 0; s < 7; ++s){
            float at = q * e[s] * EF[s];
            float lat = base + vh5r[s] + __logf(e[s]);   // == log(at)
            float G = -at * (lat + 1.f);                 // == -at*(log(at+eps)+at/(at+eps)) to ~1e-8
            pbB[s*NT + rw] = G;
            gs[s] += G;
          }
        }
        bred7(gs);
        if (tid == 0){
          for (int s = 0; s < 7; ++s){
            float T = red[0][s];
            for (int w = 1; w < 16; ++w) T += red[w][s];
            vw[s] = T;                                    // vbS stash
          }
          for (int s = 0; s < 7; ++s){
            float vb = vw[s];
            vw[s] = vb * __expf(vh[5][s] - logb[s] - mxp[5]);
            rt[s] = __expf(vh[4][s] - mxp[5]);
          }
        }
        __syncthreads();
      }

      // ---- backward t = 5..1 ----
      for (int t = 5; t >= 1; --t){
        float vwr[7], rtr[7];
        #pragma unroll
        for (int s = 0; s < 7; ++s){ vwr[s] = vw[s]; rtr[s] = rt[s]; }
        float ra[7] = {0.f,0.f,0.f,0.f,0.f,0.f,0.f};
        #pragma unroll 1
        for (int r = 0; r < 16; ++r){
          const int rw = (r << 10) | tid;
          const size_t gr = ((size_t)batch << 14) | (size_t)rw;
          float pb[7];
          #pragma unroll
          for (int s = 0; s < 7; ++s) pb[s] = pbB[s*NT + rw];
          float e[7];
          #pragma unroll
          for (int s = 0; s < 7; ++s) e[s] = ecA[(size_t)s*NROW + gr];
          const float aR = aRA[gr];
          const float rse = rseA[(size_t)(t-1)*NROW + gr];
          float ub = 0.f;
          if (t == 5){
            #pragma unroll
            for (int s = 0; s < 7; ++s) ub += pb[s];      // ubr = sum(G)
          }
          float s1 = e[0]*vwr[0];
          #pragma unroll
          for (int s = 1; s < 7; ++s) s1 += e[s]*vwr[s];
          ub -= aR * rse * s1;
          const float u2 = ub * rse;
          const float ar_ = aR * rse;
          #pragma unroll
          for (int s = 0; s < 7; ++s){
            float er = e[s] * rtr[s];
            ra[s] += u2 * er;
            pb[s] -= ar_ * vwr[s] * e[s] + u2 * er;
          }
          if (t > 1){
            #pragma unroll
            for (int s = 0; s < 7; ++s) pbB[s*NT + rw] = pb[s];
          } else {
            #pragma unroll
            for (int s = 0; s < 7; ++s)
              ecA[(size_t)s*NROW + gr] = e[s] * __expf(-pb[s]);  // c += pb
          }
        }
        if (t > 1){
          bred7(ra);
          if (tid == 0){
            for (int s = 0; s < 7; ++s){
              float T = red[0][s];
              for (int w = 1; w < 16; ++w) T += red[w][s];
              float vb = -T;
              vw[s] = vb * __expf(vh[t-1][s] - logb[s] - mxp[t-1]);
              rt[s] = __expf(vh[t-2][s] - mxp[t-1]);
            }
          }
          __syncthreads();
        } else {
          __syncthreads();
        }
      }
    } // m

    // ---- attn write (overwrites pb scratch) ----
    {
      float EF[7];
      #pragma unroll
      for (int s = 0; s < 7; ++s) EF[s] = ev[s];
      #pragma unroll 2
      for (int r = 0; r < 16; ++r){
        const int rw = (r << 10) | tid;
        const size_t gr = ((size_t)batch << 14) | (size_t)rw;
        float e[7];
        #pragma unroll
        for (int s = 0; s < 7; ++s) e[s] = ecA[(size_t)s*NROW + gr];
        const float q = aRA[gr] * rseA[(size_t)4*NROW + gr];
        #pragma unroll
        for (int s = 0; s < 7; ++s) pbB[s*NT + rw] = q * e[s] * EF[s];
      }
    }
    __syncthreads();

    // ---- updates = attn^T @ val ----
    {
      const int w = tid >> 6, d = tid & 63;
      float acc[7] = {0.f,0.f,0.f,0.f,0.f,0.f,0.f};
      const float* ab = pbB + (w << 10);
      const u16* vbp = valb + (((size_t)batch << 14) | (size_t)(w << 10))*64 + d;
      #pragma unroll 1
      for (int i = 0; i < 1024; i += 4){
        float4 a4[7];
        #pragma unroll
        for (int s = 0; s < 7; ++s) a4[s] = *(const float4*)(ab + s*NT + i);
        #pragma unroll
        for (int j = 0; j < 4; ++j){
          float vv = bflo((u32)vbp[(size_t)(i+j)*64]);
          #pragma unroll
          for (int s = 0; s < 7; ++s) acc[s] += ((const float*)&a4[s])[j] * vv;
        }
      }
      #pragma unroll
      for (int s = 0; s < 7; ++s) uacc[w][s][d] = acc[s];
    }
    __syncthreads();

    // ---- epilogue: GRU + LN + MLP (block-local) ----
    if (tid < 448){
      float u_ = 0.f;
      #pragma unroll
      for (int w = 0; w < 16; ++w) u_ += uacc[w][tid >> 6][tid & 63];
      Sl[tid>>6][tid&63] = u_;
      float sp;
      if (it == 0){
        const int d = tid & 63;
        sp = mu[d] + (fabsf(sigma[d]) + 1e-8f) * noise[batch*448 + tid];
      } else sp = Sst[tid>>6][tid&63];
      Qt[tid>>6][tid&63] = sp;
    }
    __syncthreads();
    for (int o = tid; o < 2688; o += 1024){
      const int sl = o / 384, oo = o - sl*384;
      if (oo < 192){
        const float* wr = gwih + oo*64;
        float acc2 = gbih[oo];
        #pragma unroll
        for (int dd = 0; dd < 64; ++dd) acc2 += Sl[sl][dd]*wr[dd];
        Gx[sl][oo] = acc2;
      } else {
        const int o2 = oo - 192;
        const float* wr = gwhh + o2*64;
        float acc2 = gbhh[o2];
        #pragma unroll
        for (int dd = 0; dd < 64; ++dd) acc2 += Qt[sl][dd]*wr[dd];
        Gh[sl][o2] = acc2;
      }
    }
    __syncthreads();
    if (tid < 448){
      const int s = tid >> 6, d = tid & 63;
      float r = 1.f/(1.f + __expf(-(Gx[s][d] + Gh[s][d])));
      float z = 1.f/(1.f + __expf(-(Gx[s][64+d] + Gh[s][64+d])));
      float nn2 = tanhf(Gx[s][128+d] + r*Gh[s][128+d]);
      Qn[s][d] = (1.f - z)*nn2 + z*Qt[s][d];
    }
    __syncthreads();
    if (tid < 7){
      float m2 = 0.f;
      for (int d = 0; d < 64; ++d) m2 += Qn[tid][d];
      m2 *= (1.f/64.f);
      float v2 = 0.f;
      for (int d = 0; d < 64; ++d){ float dd = Qn[tid][d]-m2; v2 += dd*dd; }
      v2 *= (1.f/64.f);
      float rs2 = rsqrtf(v2 + 1e-5f);
      for (int d = 0; d < 64; ++d)
        Sl[tid][d] = (Qn[tid][d]-m2)*rs2*lnffg[d] + lnffb[d];
    }
    __syncthreads();
    if (tid < 896){
      const int s = tid >> 7, h = tid & 127;
      const float* f1 = fc1w + h*64;
      float acc2 = fc1b[h];
      #pragma unroll
      for (int d = 0; d < 64; ++d) acc2 += Sl[s][d]*f1[d];
      H1[s][h] = fmaxf(acc2, 0.f);
    }
    __syncthreads();
    if (tid < 448){
      const int s = tid >> 6, d = tid & 63;
      const float* f2 = fc2w + d*128;
      float o2 = fc2b[d];
      #pragma unroll
      for (int h = 0; h < 128; ++h) o2 += H1[s][h]*f2[h];
      float res = Qn[s][d] + o2;
      Sst[s][d] = res;
      if (it == 2) out[batch*448 + tid] = res;
    }
    __syncthreads();
  }
}

extern "C" void kernel_launch(void* const* d_in, const int* in_sizes, int n_in,
                              void* d_out, int out_size, void* d_ws, size_t ws_size,
                              hipStream_t stream)
{
  const float* inp   = (const float*)d_in[0];
  const float* noise = (const float*)d_in[1];
  const float* mu    = (const float*)d_in[2];
  const float* sigma = (const float*)d_in[3];
  const float* Wq    = (const float*)d_in[4];
  const float* Wk    = (const float*)d_in[5];
  const float* Wv    = (const float*)d_in[6];
  const float* gwih  = (const float*)d_in[7];
  const float* gwhh  = (const float*)d_in[8];
  const float* gbih  = (const float*)d_in[9];
  const float* gbhh  = (const float*)d_in[10];
  const float* fc1w  = (const float*)d_in[11];
  const float* fc1b  = (const float*)d_in[12];
  const float* fc2w  = (const float*)d_in[13];
  const float* fc2b  = (const float*)d_in[14];
  const float* lning = (const float*)d_in[15];
  const float* lninb = (const float*)d_in[16];
  const float* lnslg = (const float*)d_in[17];
  const float* lnslb = (const float*)d_in[18];
  const float* lnffg = (const float*)d_in[19];
  const float* lnffb = (const float*)d_in[20];
  const float* wiw   = (const float*)d_in[21];
  const float* wib   = (const float*)d_in[22];
  const float* wsw   = (const float*)d_in[23];
  const float* wsb   = (const float*)d_in[24];

  char* w = (char*)d_ws;
  u16*   knb     = (u16*)(w);                     // 33,554,432 B
  u16*   valb    = (u16*)(w + 33554432);          // 33,554,432 B
  float* ecA     = (float*)(w + 67108864);        // 7*NROW*4  = 7,340,032 B
  float* rseA    = (float*)(w + 74448896);        // 5*NROW*4  = 5,242,880 B
  float* aRA     = (float*)(w + 79691776);        // NROW*4    = 1,048,576 B
  float* lgA     = (float*)(w + 80740352);        // NROW*4    = 1,048,576 B
  float* rnA     = (float*)(w + 81788928);        // NROW*4    = 1,048,576 B
  float* lsePart = (float*)(w + 82837504);        // 512*4     = 2,048 B
  // total ws usage ~= 82.84 MB

  k_pre<<<256, 1024, 0, stream>>>(inp, Wk, Wv, lning, lninb, wiw, wib,
                                  knb, valb, lgA, rnA, lsePart);
  k_mesh<<<16, 1024, 0, stream>>>(noise, mu, sigma, Wq,
                                  gwih, gwhh, gbih, gbhh,
                                  fc1w, fc1b, fc2w, fc2b,
                                  lnslg, lnslb, lnffg, lnffb, wsw, wsb,
                                  knb, valb, lgA, rnA, lsePart,
                                  ecA, rseA, aRA, (float*)d_out);
  (void)in_sizes; (void)n_in; (void)out_size; (void)ws_size;
}

// Round 3
// 2709.753 us; speedup vs baseline: 1.8751x; 1.8751x over previous
//
#include <hip/hip_runtime.h>

typedef unsigned int u32;
typedef unsigned short u16;
typedef unsigned long long u64;

#define NT 16384
#define NROW 262144            // 16 * 16384 rows total
#define LN7 1.9459101090932196f
#define ZWORDS 29696           // Tp 1024 + upT 28672 u64 words

__device__ __forceinline__ u32 f2bf(float f){
  u32 u = __float_as_uint(f);
  return (u + 0x7fffu + ((u >> 16) & 1u)) >> 16;   // RNE to bf16
}
__device__ __forceinline__ float bflo(u32 v){ return __uint_as_float(v << 16); }
__device__ __forceinline__ float bfhi(u32 v){ return __uint_as_float(v & 0xffff0000u); }

__global__ __launch_bounds__(1024) void k_zero(u64* p){
  int i = blockIdx.x * 1024 + threadIdx.x;
  if (i < ZWORDS) p[i] = 0ull;
}

// ---- sync primitives ----
// dev  = device scope (proven round-0 semantics): bypass L1+L2, MALL coherent.
// l2   = L2 scope attempt (bounded use only; may hit stale L1->no, sc0 bypasses
//        L1; may hit stale L2 line -> bounded retry then fall back to dev).
__device__ __forceinline__ void st_dev(u64* p, u64 v){
  asm volatile("global_store_dwordx2 %0, %1, off sc0 sc1" :: "v"(p), "v"(v) : "memory");
}
__device__ __forceinline__ u64 ld_dev(const u64* p){
  u64 v;
  asm volatile("global_load_dwordx2 %0, %1, off sc0 sc1\n\ts_waitcnt vmcnt(0)"
               : "=v"(v) : "v"(p) : "memory");
  return v;
}
__device__ __forceinline__ u64 ld_l2(const u64* p){
  u64 v;
  asm volatile("global_load_dwordx2 %0, %1, off sc0\n\ts_waitcnt vmcnt(0)"
               : "=v"(v) : "v"(p) : "memory");
  return v;
}

// ============================================================================
// k_pre: 256 blocks. Per row: LN(inputs), k->bf16, val->bf16, wi logit.
// (unchanged from the validated round-2 kernel)
// ============================================================================
__global__ __launch_bounds__(1024) void k_pre(
    const float* __restrict__ inp,
    const float* __restrict__ Wk, const float* __restrict__ Wv,
    const float* __restrict__ lning, const float* __restrict__ lninb,
    const float* __restrict__ wiw, const float* __restrict__ wib,
    u16* __restrict__ knb, u16* __restrict__ valb,
    float* __restrict__ lgA, float* __restrict__ rnA,
    float* __restrict__ lsePart)
{
  const int tid = threadIdx.x, blk = blockIdx.x;
  const int batch = blk >> 4, chunk = blk & 15;
  const size_t row = ((size_t)batch << 14) | (size_t)((chunk << 10) | tid);

  __shared__ float red[16][2];
  __shared__ float sbm;

  float x[64];
  {
    const float4* x4 = (const float4*)(inp + row * 64);
    #pragma unroll
    for (int i = 0; i < 16; ++i){
      float4 t = x4[i];
      x[4*i] = t.x; x[4*i+1] = t.y; x[4*i+2] = t.z; x[4*i+3] = t.w;
    }
  }
  float mean = 0.f;
  #pragma unroll
  for (int i = 0; i < 64; ++i) mean += x[i];
  mean *= (1.f/64.f);
  float var = 0.f;
  #pragma unroll
  for (int i = 0; i < 64; ++i){ float d = x[i] - mean; var += d*d; }
  var *= (1.f/64.f);
  float rstd = rsqrtf(var + 1e-5f);
  float lg = wib[0];
  #pragma unroll
  for (int i = 0; i < 64; ++i){
    x[i] = (x[i] - mean) * rstd * lning[i] + lninb[i];
    lg += x[i] * wiw[i];
  }
  {
    u32 kp[32];
    float ss = 0.f;
    #pragma unroll 4
    for (int dp = 0; dp < 64; dp += 2){
      const float4* w0 = (const float4*)(Wk + dp*64);
      const float4* w1 = (const float4*)(Wk + dp*64 + 64);
      float a0 = 0.f, a1 = 0.f;
      #pragma unroll
      for (int q = 0; q < 16; ++q){
        float4 wa = w0[q], wb = w1[q];
        a0 += x[4*q]*wa.x + x[4*q+1]*wa.y + x[4*q+2]*wa.z + x[4*q+3]*wa.w;
        a1 += x[4*q]*wb.x + x[4*q+1]*wb.y + x[4*q+2]*wb.z + x[4*q+3]*wb.w;
      }
      ss += a0*a0 + a1*a1;
      kp[dp>>1] = f2bf(a0) | (f2bf(a1) << 16);
    }
    rnA[row] = 1.f / fmaxf(sqrtf(ss), 1e-12f);
    uint4* ko = (uint4*)(knb + row*64);
    #pragma unroll
    for (int i = 0; i < 8; ++i) ko[i] = ((uint4*)kp)[i];
    #pragma unroll 4
    for (int dp = 0; dp < 64; dp += 2){
      const float4* w0 = (const float4*)(Wv + dp*64);
      const float4* w1 = (const float4*)(Wv + dp*64 + 64);
      float a0 = 0.f, a1 = 0.f;
      #pragma unroll
      for (int q = 0; q < 16; ++q){
        float4 wa = w0[q], wb = w1[q];
        a0 += x[4*q]*wa.x + x[4*q+1]*wa.y + x[4*q+2]*wa.z + x[4*q+3]*wa.w;
        a1 += x[4*q]*wb.x + x[4*q+1]*wb.y + x[4*q+2]*wb.z + x[4*q+3]*wb.w;
      }
      kp[dp>>1] = f2bf(a0) | (f2bf(a1) << 16);
    }
    uint4* vo = (uint4*)(valb + row*64);
    #pragma unroll
    for (int i = 0; i < 8; ++i) vo[i] = ((uint4*)kp)[i];
  }
  lgA[row] = lg;

  float mx = lg;
  #pragma unroll
  for (int off = 32; off > 0; off >>= 1) mx = fmaxf(mx, __shfl_xor(mx, off, 64));
  if ((tid & 63) == 0) red[tid>>6][0] = mx;
  __syncthreads();
  if (tid == 0){
    float bm = red[0][0];
    for (int w = 1; w < 16; ++w) bm = fmaxf(bm, red[w][0]);
    sbm = bm;
  }
  __syncthreads();
  float se = __expf(lg - sbm);
  #pragma unroll
  for (int off = 32; off > 0; off >>= 1) se += __shfl_xor(se, off, 64);
  if ((tid & 63) == 0) red[tid>>6][1] = se;
  __syncthreads();
  if (tid == 0){
    float S = 0.f;
    for (int w = 0; w < 16; ++w) S += red[w][1];
    lsePart[blk*2 + 0] = sbm;
    lsePart[blk*2 + 1] = S;
  }
}

// ============================================================================
// k_mesh: 64 blocks = 16 batches x 4 parties; 4096 rows/block, 4 rows/thread.
// ALL per-row state in registers (ec, pb, aR, rse5). Sinkhorn uniforms
// (evT, mxp, vh, vw, rt) in LDS. 4-party device-scope tagged sync with a
// bounded adaptive L2-scope fast path (deadlock-impossible).
// ============================================================================
__global__ __launch_bounds__(1024) void k_mesh(
    const float* __restrict__ noise, const float* __restrict__ mu,
    const float* __restrict__ sigma, const float* __restrict__ Wq,
    const float* __restrict__ gwih, const float* __restrict__ gwhh,
    const float* __restrict__ gbih, const float* __restrict__ gbhh,
    const float* __restrict__ fc1w, const float* __restrict__ fc1b,
    const float* __restrict__ fc2w, const float* __restrict__ fc2b,
    const float* __restrict__ lnslg, const float* __restrict__ lnslb,
    const float* __restrict__ lnffg, const float* __restrict__ lnffb,
    const float* __restrict__ wsw, const float* __restrict__ wsb,
    const u16* __restrict__ knb, const u16* __restrict__ valb,
    const float* __restrict__ lgA, const float* __restrict__ rnA,
    const float* __restrict__ lsePart,
    u64* Tp, u64* upT, float* out)
{
  const int tid = threadIdx.x;
  const int blk = blockIdx.x;
  // all 4 parties of a batch share blk%8 -> same XCD under round-robin dispatch
  const int batch = (blk & 7) | ((blk >> 5) << 3);
  const int party = (blk >> 3) & 3;
  const int bp    = (batch << 2) | party;
  const int rbase = party << 12;              // first row of this block

  __shared__ float Sl[7][64], Qn[7][64], Qt[7][64], Sst[7][64];
  __shared__ float Gx[7][192], Gh[7][192], H1[7][128];
  __shared__ float uacc[16][7][64];
  __shared__ float red[16][8];
  __shared__ float pol[4][8];
  __shared__ float vh[6][8], evT[6][8], logb[8], mxp[8], vw[8], rt[8];
  __shared__ float sS[2];

  float* ab = out + 7168 + (size_t)batch * 7 * NT;   // attn region (this batch)

  u32 bstep = 0;
  int tbuf = 0;
  int fastTries = 32, failcnt = 0;   // adaptive: disabled after 4 failed rounds

  // mode 0: fwd step t; mode 1: G-sum; mode 2: bwd step t
  auto redshare = [&](float* part, int mode, int t){
    #pragma unroll
    for (int off = 32; off > 0; off >>= 1)
      #pragma unroll
      for (int s = 0; s < 7; ++s) part[s] += __shfl_xor(part[s], off, 64);
    if ((tid & 63) == 0){
      const int w = tid >> 6;
      #pragma unroll
      for (int s = 0; s < 7; ++s) red[w][s] = part[s];
    }
    __syncthreads();
    ++bstep;
    if (tid < 7){
      float p = 0.f;
      #pragma unroll
      for (int w = 0; w < 16; ++w) p += red[w][tid];
      u64 word = ((u64)bstep << 32) | (u64)__float_as_uint(p);
      st_dev(&Tp[(tbuf << 9) + bp*8 + tid], word);
    }
    if (tid < 32){
      const int w = tid >> 3, j0 = tid & 7;
      const int j = (j0 == 7) ? 0 : j0;
      const u64* src = &Tp[(tbuf << 9) + ((batch << 2) + w)*8 + j];
      u64 v; bool got = false;
      for (int k = 0; k < fastTries; ++k){
        v = ld_l2(src);
        if (__all((u32)(v >> 32) == bstep)){ got = true; break; }
      }
      if (!got){
        do { v = ld_dev(src); } while (!__all((u32)(v >> 32) == bstep));
        if (++failcnt >= 4) fastTries = 0;
      }
      if (j0 < 7) pol[w][j0] = __uint_as_float((u32)v);
    }
    __syncthreads();
    if (tid == 0){
      if (mode == 0){
        for (int s = 0; s < 7; ++s){
          float T = pol[0][s] + pol[1][s] + pol[2][s] + pol[3][s];
          vh[t][s] = logb[s] + mxp[t] - __logf(T);
        }
        if (t < 5){
          float mxn = vh[t][0];
          for (int s = 1; s < 7; ++s) mxn = fmaxf(mxn, vh[t][s]);
          mxp[t+1] = mxn;
          for (int s = 0; s < 7; ++s) evT[t][s] = __expf(vh[t][s] - mxn);
        } else {
          for (int s = 0; s < 7; ++s) evT[5][s] = __expf(vh[5][s] - mxp[5]);
        }
      } else if (mode == 1){
        for (int s = 0; s < 7; ++s){
          float T = pol[0][s] + pol[1][s] + pol[2][s] + pol[3][s];
          vw[s] = T * __expf(vh[5][s] - logb[s] - mxp[5]);
          rt[s] = __expf(vh[4][s] - mxp[5]);
        }
      } else {
        for (int s = 0; s < 7; ++s){
          float T = pol[0][s] + pol[1][s] + pol[2][s] + pol[3][s];
          float vb = -T;
          vw[s] = vb * __expf(vh[t-1][s] - logb[s] - mxp[t-1]);
          rt[s] = __expf(vh[t-2][s] - mxp[t-1]);
        }
      }
    }
    tbuf ^= 1;
    __syncthreads();
  };

  // ---- init: combine batch LSE; per-row aR in registers ----
  if (tid == 0){
    float M = lsePart[batch*32];
    for (int w = 1; w < 16; ++w) M = fmaxf(M, lsePart[batch*32 + 2*w]);
    float S = 0.f;
    for (int w = 0; w < 16; ++w)
      S += __expf(lsePart[batch*32 + 2*w] - M) * lsePart[batch*32 + 2*w + 1];
    sS[0] = M + __logf(S);
  }
  __syncthreads();
  const float LSE = sS[0];

  float aR[4];
  #pragma unroll
  for (int r = 0; r < 4; ++r){
    const size_t gr = ((size_t)batch << 14) + (size_t)(rbase + (r << 10) + tid);
    aR[r] = __expf(lgA[gr] - LSE + LN7);
  }

  float ec[4][7], pb[4][7], rse5[4];

  for (int it = 0; it < 3; ++it){
    // ---- prologue: slots -> sn, logb, q, qn (block-local, redundant/party) ----
    if (tid < 448){
      float sl;
      if (it == 0){
        const int d = tid & 63;
        sl = mu[d] + (fabsf(sigma[d]) + 1e-8f) * noise[batch*448 + tid];
      } else sl = Sst[tid>>6][tid&63];
      Sl[tid>>6][tid&63] = sl;
    }
    if (tid < 8) vh[5][tid] = 0.f;
    __syncthreads();
    if (tid < 7){
      float m2 = 0.f;
      for (int d = 0; d < 64; ++d) m2 += Sl[tid][d];
      m2 *= (1.f/64.f);
      float v2 = 0.f;
      for (int d = 0; d < 64; ++d){ float dd = Sl[tid][d]-m2; v2 += dd*dd; }
      v2 *= (1.f/64.f);
      float rs2 = rsqrtf(v2 + 1e-5f);
      float lgq = wsb[0];
      for (int d = 0; d < 64; ++d){
        float s = (Sl[tid][d]-m2)*rs2*lnslg[d] + lnslb[d];
        Qt[tid][d] = s;
        lgq += s*wsw[d];
      }
      red[0][tid] = lgq;
    }
    __syncthreads();
    if (tid == 0){
      float mx = red[0][0];
      for (int s = 1; s < 7; ++s) mx = fmaxf(mx, red[0][s]);
      float sm = 0.f;
      for (int s = 0; s < 7; ++s) sm += __expf(red[0][s]-mx);
      float lse = mx + __logf(sm);
      for (int s = 0; s < 7; ++s) logb[s] = red[0][s] - lse + LN7;
    }
    __syncthreads();
    if (tid < 448){
      const int s = tid >> 6, d = tid & 63;
      const float* wr = Wq + d*64;
      float acc2 = 0.f;
      #pragma unroll
      for (int dd = 0; dd < 64; ++dd) acc2 += Qt[s][dd]*wr[dd];
      Sl[s][d] = acc2;
    }
    __syncthreads();
    if (tid < 7){
      float sq = 0.f;
      for (int d = 0; d < 64; ++d) sq += Sl[tid][d]*Sl[tid][d];
      red[1][tid] = 1.f/fmaxf(sqrtf(sq), 1e-12f);
    }
    __syncthreads();
    if (tid < 448) Qn[tid>>6][tid&63] = Sl[tid>>6][tid&63]*red[1][tid>>6];
    __syncthreads();

    // ---- C build -> ec[r][s] = exp(-c) in REGISTERS ----
    #pragma unroll
    for (int r = 0; r < 4; ++r){
      const size_t gr = ((size_t)batch << 14) + (size_t)(rbase + (r << 10) + tid);
      float acc[7] = {0.f,0.f,0.f,0.f,0.f,0.f,0.f};
      const uint4* kr = (const uint4*)(knb + gr*64);
      #pragma unroll
      for (int q8 = 0; q8 < 8; ++q8){
        uint4 kv = kr[q8];
        float f0=bflo(kv.x), f1=bfhi(kv.x), f2=bflo(kv.y), f3=bfhi(kv.y);
        float f4=bflo(kv.z), f5=bfhi(kv.z), f6=bflo(kv.w), f7=bfhi(kv.w);
        const int d0 = q8*8;
        #pragma unroll
        for (int s = 0; s < 7; ++s){
          const float4 qa = *(const float4*)&Qn[s][d0];
          const float4 qb = *(const float4*)&Qn[s][d0+4];
          acc[s] += f0*qa.x + f1*qa.y + f2*qa.z + f3*qa.w
                  + f4*qb.x + f5*qb.y + f6*qb.z + f7*qb.w;
        }
      }
      const float rn_ = rnA[gr];
      #pragma unroll
      for (int s = 0; s < 7; ++s)
        ec[r][s] = __expf(-(1.f - rn_*acc[s]));
    }

    // ---- MESH: 4 grad passes (fwd5 + G + bwd5) + final fwd5 ----
    for (int m = 0; m < 5; ++m){
      if (tid == 0){
        float mxn = vh[5][0];
        for (int s = 1; s < 7; ++s) mxn = fmaxf(mxn, vh[5][s]);
        for (int s = 0; s < 7; ++s){ vh[0][s] = vh[5][s]; evT[0][s] = __expf(vh[5][s] - mxn); }
        mxp[1] = mxn;
      }
      __syncthreads();

      #pragma unroll
      for (int t = 1; t <= 5; ++t){
        float evr[7];
        #pragma unroll
        for (int s = 0; s < 7; ++s) evr[s] = evT[t-1][s];
        float t7[7] = {0.f,0.f,0.f,0.f,0.f,0.f,0.f};
        #pragma unroll
        for (int r = 0; r < 4; ++r){
          float se = ec[r][0]*evr[0];
          #pragma unroll
          for (int s = 1; s < 7; ++s) se += ec[r][s]*evr[s];
          const float rse = 1.0f / se;
          if (t == 5) rse5[r] = rse;
          const float w = aR[r] * rse;
          #pragma unroll
          for (int s = 0; s < 7; ++s) t7[s] += w * ec[r][s];
        }
        redshare(t7, 0, t);
      }
      if (m == 4) break;

      // ---- G phase: pb = G (regs), reduce Sum(G) ----
      {
        float EF[7], vh5r[7];
        #pragma unroll
        for (int s = 0; s < 7; ++s){ EF[s] = evT[5][s]; vh5r[s] = vh[5][s]; }
        const float mx5 = mxp[5];
        float gs[7] = {0.f,0.f,0.f,0.f,0.f,0.f,0.f};
        #pragma unroll
        for (int r = 0; r < 4; ++r){
          const float q = aR[r] * rse5[r];
          const float base = __logf(aR[r]) - mx5 + __logf(rse5[r]);
          #pragma unroll
          for (int s = 0; s < 7; ++s){
            float at = q * ec[r][s] * EF[s];
            float lat = base + vh5r[s] + __logf(ec[r][s]);
            float G = -at * (lat + 1.f);
            pb[r][s] = G;
            gs[s] += G;
          }
        }
        redshare(gs, 1, 0);
      }

      // ---- backward t = 5..1 (rse recomputed from evT) ----
      #pragma unroll
      for (int t = 5; t >= 1; --t){
        float vwr[7], rtr[7], evr[7];
        #pragma unroll
        for (int s = 0; s < 7; ++s){ vwr[s] = vw[s]; rtr[s] = rt[s]; evr[s] = evT[t-1][s]; }
        float ra[7] = {0.f,0.f,0.f,0.f,0.f,0.f,0.f};
        #pragma unroll
        for (int r = 0; r < 4; ++r){
          float se = ec[r][0]*evr[0];
          #pragma unroll
          for (int s = 1; s < 7; ++s) se += ec[r][s]*evr[s];
          const float rse = 1.0f / se;
          float ub = 0.f;
          if (t == 5){
            #pragma unroll
            for (int s = 0; s < 7; ++s) ub += pb[r][s];
          }
          float s1 = ec[r][0]*vwr[0];
          #pragma unroll
          for (int s = 1; s < 7; ++s) s1 += ec[r][s]*vwr[s];
          ub -= aR[r] * rse * s1;
          const float u2 = ub * rse;
          const float ar_ = aR[r] * rse;
          #pragma unroll
          for (int s = 0; s < 7; ++s){
            float er = ec[r][s] * rtr[s];
            ra[s] += u2 * er;
            pb[r][s] -= ar_ * vwr[s] * ec[r][s] + u2 * er;
          }
          if (t == 1){
            #pragma unroll
            for (int s = 0; s < 7; ++s)
              ec[r][s] = ec[r][s] * __expf(-pb[r][s]);   // c += pb
          }
        }
        if (t > 1) redshare(ra, 2, t);
        else       __syncthreads();   // guard evT/vw/rt reads vs next m's writes
      }
    } // m

    // ---- attn write (final transport plan), straight from registers ----
    {
      float EF[7];
      #pragma unroll
      for (int s = 0; s < 7; ++s) EF[s] = evT[5][s];
      #pragma unroll
      for (int r = 0; r < 4; ++r){
        const int n = rbase + (r << 10) + tid;
        const float wq = aR[r] * rse5[r];
        #pragma unroll
        for (int s = 0; s < 7; ++s) ab[s*NT + n] = wq * ec[r][s] * EF[s];
      }
    }
    __syncthreads();   // drains vmem: attn visible to own block's L2 reads

    // ---- updates partial = attn^T @ val over this block's 4096 rows ----
    {
      const int w = tid >> 6, d = tid & 63;
      const int nb = rbase + (w << 8);
      float acc[7] = {0.f,0.f,0.f,0.f,0.f,0.f,0.f};
      const u16* vbp = valb + (((size_t)batch << 14) + (size_t)nb)*64 + d;
      #pragma unroll 1
      for (int i = 0; i < 256; i += 4){
        float4 a4[7];
        #pragma unroll
        for (int s = 0; s < 7; ++s) a4[s] = *(const float4*)(ab + s*NT + nb + i);
        #pragma unroll
        for (int j = 0; j < 4; ++j){
          float vv = bflo((u32)vbp[(size_t)(i+j)*64]);
          #pragma unroll
          for (int s = 0; s < 7; ++s) acc[s] += ((const float*)&a4[s])[j] * vv;
        }
      }
      #pragma unroll
      for (int s = 0; s < 7; ++s) uacc[w][s][d] = acc[s];
    }
    __syncthreads();

    // ---- cross-party sum of updates (4-party tagged sync, device scope) ----
    ++bstep;
    if (tid < 448){
      float u_ = 0.f;
      #pragma unroll
      for (int w = 0; w < 16; ++w) u_ += uacc[w][tid >> 6][tid & 63];
      u64 word = ((u64)bstep << 32) | (u64)__float_as_uint(u_);
      st_dev(&upT[(size_t)bp*448 + tid], word);
      u64 vv[4];
      bool ok;
      do{
        ok = true;
        #pragma unroll
        for (int p = 0; p < 4; ++p){
          vv[p] = ld_dev(&upT[(size_t)((batch << 2) + p)*448 + tid]);
          ok = ok && ((u32)(vv[p] >> 32) == bstep);
        }
      } while (!__all(ok));
      float u_t = 0.f;
      #pragma unroll
      for (int p = 0; p < 4; ++p) u_t += __uint_as_float((u32)vv[p]);
      Sl[tid>>6][tid&63] = u_t;                                  // updates
      float sp;
      if (it == 0){
        const int d = tid & 63;
        sp = mu[d] + (fabsf(sigma[d]) + 1e-8f) * noise[batch*448 + tid];
      } else sp = Sst[tid>>6][tid&63];
      Qt[tid>>6][tid&63] = sp;                                   // slots_prev
    }
    __syncthreads();

    // ---- epilogue: GRU + LN + MLP (block-local, redundant per party) ----
    for (int o = tid; o < 2688; o += 1024){
      const int sl = o / 384, oo = o - sl*384;
      if (oo < 192){
        const float* wr = gwih + oo*64;
        float acc2 = gbih[oo];
        #pragma unroll
        for (int dd = 0; dd < 64; ++dd) acc2 += Sl[sl][dd]*wr[dd];
        Gx[sl][oo] = acc2;
      } else {
        const int o2 = oo - 192;
        const float* wr = gwhh + o2*64;
        float acc2 = gbhh[o2];
        #pragma unroll
        for (int dd = 0; dd < 64; ++dd) acc2 += Qt[sl][dd]*wr[dd];
        Gh[sl][o2] = acc2;
      }
    }
    __syncthreads();
    if (tid < 448){
      const int s = tid >> 6, d = tid & 63;
      float r = 1.f/(1.f + __expf(-(Gx[s][d] + Gh[s][d])));
      float z = 1.f/(1.f + __expf(-(Gx[s][64+d] + Gh[s][64+d])));
      float nn2 = tanhf(Gx[s][128+d] + r*Gh[s][128+d]);
      Qn[s][d] = (1.f - z)*nn2 + z*Qt[s][d];
    }
    __syncthreads();
    if (tid < 7){
      float m2 = 0.f;
      for (int d = 0; d < 64; ++d) m2 += Qn[tid][d];
      m2 *= (1.f/64.f);
      float v2 = 0.f;
      for (int d = 0; d < 64; ++d){ float dd = Qn[tid][d]-m2; v2 += dd*dd; }
      v2 *= (1.f/64.f);
      float rs2 = rsqrtf(v2 + 1e-5f);
      for (int d = 0; d < 64; ++d)
        Sl[tid][d] = (Qn[tid][d]-m2)*rs2*lnffg[d] + lnffb[d];
    }
    __syncthreads();
    if (tid < 896){
      const int s = tid >> 7, h = tid & 127;
      const float* f1 = fc1w + h*64;
      float acc2 = fc1b[h];
      #pragma unroll
      for (int d = 0; d < 64; ++d) acc2 += Sl[s][d]*f1[d];
      H1[s][h] = fmaxf(acc2, 0.f);
    }
    __syncthreads();
    if (tid < 448){
      const int s = tid >> 6, d = tid & 63;
      const float* f2 = fc2w + d*128;
      float o2 = fc2b[d];
      #pragma unroll
      for (int h = 0; h < 128; ++h) o2 += H1[s][h]*f2[h];
      float res = Qn[s][d] + o2;
      Sst[s][d] = res;
      if (it == 2 && party == 0) out[batch*448 + tid] = res;
    }
    __syncthreads();
  }
}

extern "C" void kernel_launch(void* const* d_in, const int* in_sizes, int n_in,
                              void* d_out, int out_size, void* d_ws, size_t ws_size,
                              hipStream_t stream)
{
  const float* inp   = (const float*)d_in[0];
  const float* noise = (const float*)d_in[1];
  const float* mu    = (const float*)d_in[2];
  const float* sigma = (const float*)d_in[3];
  const float* Wq    = (const float*)d_in[4];
  const float* Wk    = (const float*)d_in[5];
  const float* Wv    = (const float*)d_in[6];
  const float* gwih  = (const float*)d_in[7];
  const float* gwhh  = (const float*)d_in[8];
  const float* gbih  = (const float*)d_in[9];
  const float* gbhh  = (const float*)d_in[10];
  const float* fc1w  = (const float*)d_in[11];
  const float* fc1b  = (const float*)d_in[12];
  const float* fc2w  = (const float*)d_in[13];
  const float* fc2b  = (const float*)d_in[14];
  const float* lning = (const float*)d_in[15];
  const float* lninb = (const float*)d_in[16];
  const float* lnslg = (const float*)d_in[17];
  const float* lnslb = (const float*)d_in[18];
  const float* lnffg = (const float*)d_in[19];
  const float* lnffb = (const float*)d_in[20];
  const float* wiw   = (const float*)d_in[21];
  const float* wib   = (const float*)d_in[22];
  const float* wsw   = (const float*)d_in[23];
  const float* wsb   = (const float*)d_in[24];

  char* w = (char*)d_ws;
  u16*   knb     = (u16*)(w);                     // 33,554,432 B
  u16*   valb    = (u16*)(w + 33554432);          // 33,554,432 B
  float* lgA     = (float*)(w + 67108864);        // 1,048,576 B
  float* rnA     = (float*)(w + 68157440);        // 1,048,576 B
  float* lsePart = (float*)(w + 69206016);        // 2,048 B
  u64*   Tp      = (u64*)(w + 69208064);          // 2*64*8*8 = 8,192 B
  u64*   upT     = (u64*)(w + 69216256);          // 64*448*8 = 229,376 B
  // total ws usage ~= 66.2 MB

  k_zero<<<29, 1024, 0, stream>>>(Tp);
  k_pre<<<256, 1024, 0, stream>>>(inp, Wk, Wv, lning, lninb, wiw, wib,
                                  knb, valb, lgA, rnA, lsePart);
  k_mesh<<<64, 1024, 0, stream>>>(noise, mu, sigma, Wq,
                                  gwih, gwhh, gbih, gbhh,
                                  fc1w, fc1b, fc2w, fc2b,
                                  lnslg, lnslb, lnffg, lnffb, wsw, wsb,
                                  knb, valb, lgA, rnA, lsePart,
                                  Tp, upT, (float*)d_out);
  (void)in_sizes; (void)n_in; (void)out_size; (void)ws_size;
}

// Round 4
// 2100.200 us; speedup vs baseline: 2.4194x; 1.2902x over previous
//
#include <hip/hip_runtime.h>

typedef unsigned int u32;
typedef unsigned short u16;
typedef unsigned long long u64;

#define NT 16384
#define LN7 1.9459101090932196f
#define ZWORDS 59392           // Tp 2048 + upT 57344 u64 words

__device__ __forceinline__ u32 f2bf(float f){
  u32 u = __float_as_uint(f);
  return (u + 0x7fffu + ((u >> 16) & 1u)) >> 16;   // RNE to bf16
}
__device__ __forceinline__ float bflo(u32 v){ return __uint_as_float(v << 16); }
__device__ __forceinline__ float bfhi(u32 v){ return __uint_as_float(v & 0xffff0000u); }

__global__ __launch_bounds__(1024) void k_zero(u64* p){
  int i = blockIdx.x * 1024 + threadIdx.x;
  if (i < ZWORDS) p[i] = 0ull;
}

// ---- sync primitives (proven in rounds 0/3) ----
__device__ __forceinline__ void st_dev(u64* p, u64 v){
  asm volatile("global_store_dwordx2 %0, %1, off sc0 sc1" :: "v"(p), "v"(v) : "memory");
}
__device__ __forceinline__ u64 ld_dev(const u64* p){
  u64 v;
  asm volatile("global_load_dwordx2 %0, %1, off sc0 sc1\n\ts_waitcnt vmcnt(0)"
               : "=v"(v) : "v"(p) : "memory");
  return v;
}
__device__ __forceinline__ u64 ld_l2(const u64* p){
  u64 v;
  asm volatile("global_load_dwordx2 %0, %1, off sc0\n\ts_waitcnt vmcnt(0)"
               : "=v"(v) : "v"(p) : "memory");
  return v;
}
__device__ __forceinline__ u64 ld_issue(const u64* p){
  u64 v;
  asm volatile("global_load_dwordx2 %0, %1, off sc0 sc1" : "=v"(v) : "v"(p));
  return v;
}

// ============================================================================
// k_pre: 256 blocks. Per row: LN(inputs), k->bf16, val->bf16, wi logit.
// 128-VGPR budget (x[64]+kp[32] live) -> no spill.
// ============================================================================
__global__ __launch_bounds__(1024, 4) void k_pre(
    const float* __restrict__ inp,
    const float* __restrict__ Wk, const float* __restrict__ Wv,
    const float* __restrict__ lning, const float* __restrict__ lninb,
    const float* __restrict__ wiw, const float* __restrict__ wib,
    u16* __restrict__ knb, u16* __restrict__ valb,
    float* __restrict__ lgA, float* __restrict__ rnA,
    float* __restrict__ lsePart)
{
  const int tid = threadIdx.x, blk = blockIdx.x;
  const int batch = blk >> 4, chunk = blk & 15;
  const size_t row = ((size_t)batch << 14) | (size_t)((chunk << 10) | tid);

  __shared__ float red[16][2];
  __shared__ float sbm;

  float x[64];
  {
    const float4* x4 = (const float4*)(inp + row * 64);
    #pragma unroll
    for (int i = 0; i < 16; ++i){
      float4 t = x4[i];
      x[4*i] = t.x; x[4*i+1] = t.y; x[4*i+2] = t.z; x[4*i+3] = t.w;
    }
  }
  float mean = 0.f;
  #pragma unroll
  for (int i = 0; i < 64; ++i) mean += x[i];
  mean *= (1.f/64.f);
  float var = 0.f;
  #pragma unroll
  for (int i = 0; i < 64; ++i){ float d = x[i] - mean; var += d*d; }
  var *= (1.f/64.f);
  float rstd = rsqrtf(var + 1e-5f);
  float lg = wib[0];
  #pragma unroll
  for (int i = 0; i < 64; ++i){
    x[i] = (x[i] - mean) * rstd * lning[i] + lninb[i];
    lg += x[i] * wiw[i];
  }
  {
    u32 kp[32];
    float ss = 0.f;
    #pragma unroll 4
    for (int dp = 0; dp < 64; dp += 2){
      const float4* w0 = (const float4*)(Wk + dp*64);
      const float4* w1 = (const float4*)(Wk + dp*64 + 64);
      float a0 = 0.f, a1 = 0.f;
      #pragma unroll
      for (int q = 0; q < 16; ++q){
        float4 wa = w0[q], wb = w1[q];
        a0 += x[4*q]*wa.x + x[4*q+1]*wa.y + x[4*q+2]*wa.z + x[4*q+3]*wa.w;
        a1 += x[4*q]*wb.x + x[4*q+1]*wb.y + x[4*q+2]*wb.z + x[4*q+3]*wb.w;
      }
      ss += a0*a0 + a1*a1;
      kp[dp>>1] = f2bf(a0) | (f2bf(a1) << 16);
    }
    rnA[row] = 1.f / fmaxf(sqrtf(ss), 1e-12f);
    uint4* ko = (uint4*)(knb + row*64);
    #pragma unroll
    for (int i = 0; i < 8; ++i) ko[i] = ((uint4*)kp)[i];
    #pragma unroll 4
    for (int dp = 0; dp < 64; dp += 2){
      const float4* w0 = (const float4*)(Wv + dp*64);
      const float4* w1 = (const float4*)(Wv + dp*64 + 64);
      float a0 = 0.f, a1 = 0.f;
      #pragma unroll
      for (int q = 0; q < 16; ++q){
        float4 wa = w0[q], wb = w1[q];
        a0 += x[4*q]*wa.x + x[4*q+1]*wa.y + x[4*q+2]*wa.z + x[4*q+3]*wa.w;
        a1 += x[4*q]*wb.x + x[4*q+1]*wb.y + x[4*q+2]*wb.z + x[4*q+3]*wb.w;
      }
      kp[dp>>1] = f2bf(a0) | (f2bf(a1) << 16);
    }
    uint4* vo = (uint4*)(valb + row*64);
    #pragma unroll
    for (int i = 0; i < 8; ++i) vo[i] = ((uint4*)kp)[i];
  }
  lgA[row] = lg;

  float mx = lg;
  #pragma unroll
  for (int off = 32; off > 0; off >>= 1) mx = fmaxf(mx, __shfl_xor(mx, off, 64));
  if ((tid & 63) == 0) red[tid>>6][0] = mx;
  __syncthreads();
  if (tid == 0){
    float bm = red[0][0];
    for (int w = 1; w < 16; ++w) bm = fmaxf(bm, red[w][0]);
    sbm = bm;
  }
  __syncthreads();
  float se = __expf(lg - sbm);
  #pragma unroll
  for (int off = 32; off > 0; off >>= 1) se += __shfl_xor(se, off, 64);
  if ((tid & 63) == 0) red[tid>>6][1] = se;
  __syncthreads();
  if (tid == 0){
    float S = 0.f;
    for (int w = 0; w < 16; ++w) S += red[w][1];
    lsePart[blk*2 + 0] = sbm;
    lsePart[blk*2 + 1] = S;
  }
}

// ============================================================================
// k_mesh: 128 blocks = 16 batches x 8 parties; 2048 rows/block, 2 rows/thread.
// ALL per-row state in registers (~34 floats/thread, 128-VGPR budget).
// 8-party device-scope tagged sync + bounded L2 fast path.
// ============================================================================
__global__ __launch_bounds__(1024, 4) void k_mesh(
    const float* __restrict__ noise, const float* __restrict__ mu,
    const float* __restrict__ sigma, const float* __restrict__ Wq,
    const float* __restrict__ gwih, const float* __restrict__ gwhh,
    const float* __restrict__ gbih, const float* __restrict__ gbhh,
    const float* __restrict__ fc1w, const float* __restrict__ fc1b,
    const float* __restrict__ fc2w, const float* __restrict__ fc2b,
    const float* __restrict__ lnslg, const float* __restrict__ lnslb,
    const float* __restrict__ lnffg, const float* __restrict__ lnffb,
    const float* __restrict__ wsw, const float* __restrict__ wsb,
    const u16* __restrict__ knb, const u16* __restrict__ valb,
    const float* __restrict__ lgA, const float* __restrict__ rnA,
    const float* __restrict__ lsePart,
    u64* Tp, u64* upT, float* out)
{
  const int tid = threadIdx.x;
  const int blk = blockIdx.x;
  // all 8 parties of a batch share blk%8 -> same XCD under round-robin dispatch
  const int batch = (blk & 7) | ((blk >> 6) << 3);
  const int party = (blk >> 3) & 7;
  const int bp    = (batch << 3) | party;
  const int rbase = party << 11;              // first row of this block

  __shared__ float Sl[7][64], Qn[7][64], Qt[7][64], Sst[7][64];
  __shared__ float Gx[7][192], Gh[7][192], H1[7][128];
  __shared__ float uacc[16][7][64];
  __shared__ float red[16][8];
  __shared__ float pol[8][8];
  __shared__ float vh[6][8], evT[6][8], logb[8], mxp[8], vw[8], rt[8];
  __shared__ float sS[2];

  float* ab = out + 7168 + (size_t)batch * 7 * NT;   // attn region (this batch)

  u32 bstep = 0;
  int tbuf = 0;
  int fastTries = 32, failcnt = 0;   // adaptive: disabled after 4 failed rounds

  // mode 0: fwd step t; mode 1: G-sum; mode 2: bwd step t
  auto redshare = [&](float* part, int mode, int t){
    #pragma unroll
    for (int off = 32; off > 0; off >>= 1)
      #pragma unroll
      for (int s = 0; s < 7; ++s) part[s] += __shfl_xor(part[s], off, 64);
    if ((tid & 63) == 0){
      const int w = tid >> 6;
      #pragma unroll
      for (int s = 0; s < 7; ++s) red[w][s] = part[s];
    }
    __syncthreads();
    ++bstep;
    if (tid < 7){
      float p = 0.f;
      #pragma unroll
      for (int w = 0; w < 16; ++w) p += red[w][tid];
      u64 word = ((u64)bstep << 32) | (u64)__float_as_uint(p);
      st_dev(&Tp[(tbuf << 10) + bp*8 + tid], word);
    }
    if (tid < 64){
      const int w = tid >> 3, j0 = tid & 7;
      const int j = (j0 == 7) ? 0 : j0;
      const u64* src = &Tp[(tbuf << 10) + ((batch << 3) + w)*8 + j];
      u64 v; bool got = false;
      for (int k = 0; k < fastTries; ++k){
        v = ld_l2(src);
        if (__all((u32)(v >> 32) == bstep)){ got = true; break; }
      }
      if (!got){
        do { v = ld_dev(src); } while (!__all((u32)(v >> 32) == bstep));
        if (++failcnt >= 4) fastTries = 0;
      }
      if (j0 < 7) pol[w][j0] = __uint_as_float((u32)v);
    }
    __syncthreads();
    if (tid == 0){
      if (mode == 0){
        for (int s = 0; s < 7; ++s){
          float T = pol[0][s] + pol[1][s] + pol[2][s] + pol[3][s]
                  + pol[4][s] + pol[5][s] + pol[6][s] + pol[7][s];
          vh[t][s] = logb[s] + mxp[t] - __logf(T);
        }
        if (t < 5){
          float mxn = vh[t][0];
          for (int s = 1; s < 7; ++s) mxn = fmaxf(mxn, vh[t][s]);
          mxp[t+1] = mxn;
          for (int s = 0; s < 7; ++s) evT[t][s] = __expf(vh[t][s] - mxn);
        } else {
          for (int s = 0; s < 7; ++s) evT[5][s] = __expf(vh[5][s] - mxp[5]);
        }
      } else if (mode == 1){
        for (int s = 0; s < 7; ++s){
          float T = pol[0][s] + pol[1][s] + pol[2][s] + pol[3][s]
                  + pol[4][s] + pol[5][s] + pol[6][s] + pol[7][s];
          vw[s] = T * __expf(vh[5][s] - logb[s] - mxp[5]);
          rt[s] = __expf(vh[4][s] - mxp[5]);
        }
      } else {
        for (int s = 0; s < 7; ++s){
          float T = pol[0][s] + pol[1][s] + pol[2][s] + pol[3][s]
                  + pol[4][s] + pol[5][s] + pol[6][s] + pol[7][s];
          float vb = -T;
          vw[s] = vb * __expf(vh[t-1][s] - logb[s] - mxp[t-1]);
          rt[s] = __expf(vh[t-2][s] - mxp[t-1]);
        }
      }
    }
    tbuf ^= 1;
    __syncthreads();
  };

  // ---- init: combine batch LSE; per-row aR in registers ----
  if (tid == 0){
    float M = lsePart[batch*32];
    for (int w = 1; w < 16; ++w) M = fmaxf(M, lsePart[batch*32 + 2*w]);
    float S = 0.f;
    for (int w = 0; w < 16; ++w)
      S += __expf(lsePart[batch*32 + 2*w] - M) * lsePart[batch*32 + 2*w + 1];
    sS[0] = M + __logf(S);
  }
  __syncthreads();
  const float LSE = sS[0];

  float aR[2];
  #pragma unroll
  for (int r = 0; r < 2; ++r){
    const size_t gr = ((size_t)batch << 14) + (size_t)(rbase + (r << 10) + tid);
    aR[r] = __expf(lgA[gr] - LSE + LN7);
  }

  float ec[2][7], pb[2][7], rse5[2];

  for (int it = 0; it < 3; ++it){
    // ---- prologue: slots -> sn, logb, q, qn (block-local, redundant/party) ----
    if (tid < 448){
      float sl;
      if (it == 0){
        const int d = tid & 63;
        sl = mu[d] + (fabsf(sigma[d]) + 1e-8f) * noise[batch*448 + tid];
      } else sl = Sst[tid>>6][tid&63];
      Sl[tid>>6][tid&63] = sl;
    }
    if (tid < 8) vh[5][tid] = 0.f;
    __syncthreads();
    if (tid < 7){
      float m2 = 0.f;
      for (int d = 0; d < 64; ++d) m2 += Sl[tid][d];
      m2 *= (1.f/64.f);
      float v2 = 0.f;
      for (int d = 0; d < 64; ++d){ float dd = Sl[tid][d]-m2; v2 += dd*dd; }
      v2 *= (1.f/64.f);
      float rs2 = rsqrtf(v2 + 1e-5f);
      float lgq = wsb[0];
      for (int d = 0; d < 64; ++d){
        float s = (Sl[tid][d]-m2)*rs2*lnslg[d] + lnslb[d];
        Qt[tid][d] = s;
        lgq += s*wsw[d];
      }
      red[0][tid] = lgq;
    }
    __syncthreads();
    if (tid == 0){
      float mx = red[0][0];
      for (int s = 1; s < 7; ++s) mx = fmaxf(mx, red[0][s]);
      float sm = 0.f;
      for (int s = 0; s < 7; ++s) sm += __expf(red[0][s]-mx);
      float lse = mx + __logf(sm);
      for (int s = 0; s < 7; ++s) logb[s] = red[0][s] - lse + LN7;
    }
    __syncthreads();
    if (tid < 448){
      const int s = tid >> 6, d = tid & 63;
      const float* wr = Wq + d*64;
      float acc2 = 0.f;
      #pragma unroll
      for (int dd = 0; dd < 64; ++dd) acc2 += Qt[s][dd]*wr[dd];
      Sl[s][d] = acc2;
    }
    __syncthreads();
    if (tid < 7){
      float sq = 0.f;
      for (int d = 0; d < 64; ++d) sq += Sl[tid][d]*Sl[tid][d];
      red[1][tid] = 1.f/fmaxf(sqrtf(sq), 1e-12f);
    }
    __syncthreads();
    if (tid < 448) Qn[tid>>6][tid&63] = Sl[tid>>6][tid&63]*red[1][tid>>6];
    __syncthreads();

    // ---- C build -> ec[r][s] = exp(-c) in REGISTERS ----
    #pragma unroll
    for (int r = 0; r < 2; ++r){
      const size_t gr = ((size_t)batch << 14) + (size_t)(rbase + (r << 10) + tid);
      float acc[7] = {0.f,0.f,0.f,0.f,0.f,0.f,0.f};
      const uint4* kr = (const uint4*)(knb + gr*64);
      #pragma unroll
      for (int q8 = 0; q8 < 8; ++q8){
        uint4 kv = kr[q8];
        float f0=bflo(kv.x), f1=bfhi(kv.x), f2=bflo(kv.y), f3=bfhi(kv.y);
        float f4=bflo(kv.z), f5=bfhi(kv.z), f6=bflo(kv.w), f7=bfhi(kv.w);
        const int d0 = q8*8;
        #pragma unroll
        for (int s = 0; s < 7; ++s){
          const float4 qa = *(const float4*)&Qn[s][d0];
          const float4 qb = *(const float4*)&Qn[s][d0+4];
          acc[s] += f0*qa.x + f1*qa.y + f2*qa.z + f3*qa.w
                  + f4*qb.x + f5*qb.y + f6*qb.z + f7*qb.w;
        }
      }
      const float rn_ = rnA[gr];
      #pragma unroll
      for (int s = 0; s < 7; ++s)
        ec[r][s] = __expf(-(1.f - rn_*acc[s]));
    }

    // ---- MESH: 4 grad passes (fwd5 + G + bwd5) + final fwd5 ----
    for (int m = 0; m < 5; ++m){
      if (tid == 0){
        float mxn = vh[5][0];
        for (int s = 1; s < 7; ++s) mxn = fmaxf(mxn, vh[5][s]);
        for (int s = 0; s < 7; ++s){ vh[0][s] = vh[5][s]; evT[0][s] = __expf(vh[5][s] - mxn); }
        mxp[1] = mxn;
      }
      __syncthreads();

      #pragma unroll
      for (int t = 1; t <= 5; ++t){
        float evr[7];
        #pragma unroll
        for (int s = 0; s < 7; ++s) evr[s] = evT[t-1][s];
        float t7[7] = {0.f,0.f,0.f,0.f,0.f,0.f,0.f};
        #pragma unroll
        for (int r = 0; r < 2; ++r){
          float se = ec[r][0]*evr[0];
          #pragma unroll
          for (int s = 1; s < 7; ++s) se += ec[r][s]*evr[s];
          const float rse = 1.0f / se;
          if (t == 5) rse5[r] = rse;
          const float w = aR[r] * rse;
          #pragma unroll
          for (int s = 0; s < 7; ++s) t7[s] += w * ec[r][s];
        }
        redshare(t7, 0, t);
      }
      if (m == 4) break;

      // ---- G phase: pb = G (regs), reduce Sum(G) ----
      {
        float EF[7], vh5r[7];
        #pragma unroll
        for (int s = 0; s < 7; ++s){ EF[s] = evT[5][s]; vh5r[s] = vh[5][s]; }
        const float mx5 = mxp[5];
        float gs[7] = {0.f,0.f,0.f,0.f,0.f,0.f,0.f};
        #pragma unroll
        for (int r = 0; r < 2; ++r){
          const float q = aR[r] * rse5[r];
          const float base = __logf(aR[r]) - mx5 + __logf(rse5[r]);
          #pragma unroll
          for (int s = 0; s < 7; ++s){
            float at = q * ec[r][s] * EF[s];
            float lat = base + vh5r[s] + __logf(ec[r][s]);
            float G = -at * (lat + 1.f);
            pb[r][s] = G;
            gs[s] += G;
          }
        }
        redshare(gs, 1, 0);
      }

      // ---- backward t = 5..1 (rse recomputed from evT) ----
      #pragma unroll
      for (int t = 5; t >= 1; --t){
        float vwr[7], rtr[7], evr[7];
        #pragma unroll
        for (int s = 0; s < 7; ++s){ vwr[s] = vw[s]; rtr[s] = rt[s]; evr[s] = evT[t-1][s]; }
        float ra[7] = {0.f,0.f,0.f,0.f,0.f,0.f,0.f};
        #pragma unroll
        for (int r = 0; r < 2; ++r){
          float se = ec[r][0]*evr[0];
          #pragma unroll
          for (int s = 1; s < 7; ++s) se += ec[r][s]*evr[s];
          const float rse = 1.0f / se;
          float ub = 0.f;
          if (t == 5){
            #pragma unroll
            for (int s = 0; s < 7; ++s) ub += pb[r][s];
          }
          float s1 = ec[r][0]*vwr[0];
          #pragma unroll
          for (int s = 1; s < 7; ++s) s1 += ec[r][s]*vwr[s];
          ub -= aR[r] * rse * s1;
          const float u2 = ub * rse;
          const float ar_ = aR[r] * rse;
          #pragma unroll
          for (int s = 0; s < 7; ++s){
            float er = ec[r][s] * rtr[s];
            ra[s] += u2 * er;
            pb[r][s] -= ar_ * vwr[s] * ec[r][s] + u2 * er;
          }
          if (t == 1){
            #pragma unroll
            for (int s = 0; s < 7; ++s)
              ec[r][s] = ec[r][s] * __expf(-pb[r][s]);   // c += pb
          }
        }
        if (t > 1) redshare(ra, 2, t);
        else       __syncthreads();   // guard evT/vw/rt reads vs next m's writes
      }
    } // m

    // ---- attn write (final transport plan), straight from registers ----
    {
      float EF[7];
      #pragma unroll
      for (int s = 0; s < 7; ++s) EF[s] = evT[5][s];
      #pragma unroll
      for (int r = 0; r < 2; ++r){
        const int n = rbase + (r << 10) + tid;
        const float wq = aR[r] * rse5[r];
        #pragma unroll
        for (int s = 0; s < 7; ++s) ab[s*NT + n] = wq * ec[r][s] * EF[s];
      }
    }
    __syncthreads();

    // ---- updates partial = attn^T @ val over this block's 2048 rows ----
    {
      const int w = tid >> 6, d = tid & 63;
      const int nb = rbase + (w << 7);
      float acc[7] = {0.f,0.f,0.f,0.f,0.f,0.f,0.f};
      const u16* vbp = valb + (((size_t)batch << 14) + (size_t)nb)*64 + d;
      #pragma unroll 1
      for (int i = 0; i < 128; i += 4){
        float4 a4[7];
        #pragma unroll
        for (int s = 0; s < 7; ++s) a4[s] = *(const float4*)(ab + s*NT + nb + i);
        #pragma unroll
        for (int j = 0; j < 4; ++j){
          float vv = bflo((u32)vbp[(size_t)(i+j)*64]);
          #pragma unroll
          for (int s = 0; s < 7; ++s) acc[s] += ((const float*)&a4[s])[j] * vv;
        }
      }
      #pragma unroll
      for (int s = 0; s < 7; ++s) uacc[w][s][d] = acc[s];
    }
    __syncthreads();

    // ---- cross-party sum of updates (8-party tagged sync, device scope) ----
    ++bstep;
    if (tid < 448){
      float u_ = 0.f;
      #pragma unroll
      for (int w = 0; w < 16; ++w) u_ += uacc[w][tid >> 6][tid & 63];
      u64 word = ((u64)bstep << 32) | (u64)__float_as_uint(u_);
      st_dev(&upT[(size_t)bp*448 + tid], word);
      const u64* base = &upT[(size_t)(batch << 3)*448 + tid];
      u64 vv[8];
      bool ok;
      do{
        #pragma unroll
        for (int p = 0; p < 8; ++p) vv[p] = ld_issue(base + p*448);
        asm volatile("s_waitcnt vmcnt(0)"
          : "+v"(vv[0]),"+v"(vv[1]),"+v"(vv[2]),"+v"(vv[3]),
            "+v"(vv[4]),"+v"(vv[5]),"+v"(vv[6]),"+v"(vv[7])
          :: "memory");
        ok = true;
        #pragma unroll
        for (int p = 0; p < 8; ++p) ok = ok && ((u32)(vv[p] >> 32) == bstep);
      } while (!__all(ok));
      float u_t = 0.f;
      #pragma unroll
      for (int p = 0; p < 8; ++p) u_t += __uint_as_float((u32)vv[p]);
      Sl[tid>>6][tid&63] = u_t;                                  // updates
      float sp;
      if (it == 0){
        const int d = tid & 63;
        sp = mu[d] + (fabsf(sigma[d]) + 1e-8f) * noise[batch*448 + tid];
      } else sp = Sst[tid>>6][tid&63];
      Qt[tid>>6][tid&63] = sp;                                   // slots_prev
    }
    __syncthreads();

    // ---- epilogue: GRU + LN + MLP (block-local, redundant per party) ----
    for (int o = tid; o < 2688; o += 1024){
      const int sl = o / 384, oo = o - sl*384;
      if (oo < 192){
        const float* wr = gwih + oo*64;
        float acc2 = gbih[oo];
        #pragma unroll
        for (int dd = 0; dd < 64; ++dd) acc2 += Sl[sl][dd]*wr[dd];
        Gx[sl][oo] = acc2;
      } else {
        const int o2 = oo - 192;
        const float* wr = gwhh + o2*64;
        float acc2 = gbhh[o2];
        #pragma unroll
        for (int dd = 0; dd < 64; ++dd) acc2 += Qt[sl][dd]*wr[dd];
        Gh[sl][o2] = acc2;
      }
    }
    __syncthreads();
    if (tid < 448){
      const int s = tid >> 6, d = tid & 63;
      float r = 1.f/(1.f + __expf(-(Gx[s][d] + Gh[s][d])));
      float z = 1.f/(1.f + __expf(-(Gx[s][64+d] + Gh[s][64+d])));
      float nn2 = tanhf(Gx[s][128+d] + r*Gh[s][128+d]);
      Qn[s][d] = (1.f - z)*nn2 + z*Qt[s][d];
    }
    __syncthreads();
    if (tid < 7){
      float m2 = 0.f;
      for (int d = 0; d < 64; ++d) m2 += Qn[tid][d];
      m2 *= (1.f/64.f);
      float v2 = 0.f;
      for (int d = 0; d < 64; ++d){ float dd = Qn[tid][d]-m2; v2 += dd*dd; }
      v2 *= (1.f/64.f);
      float rs2 = rsqrtf(v2 + 1e-5f);
      for (int d = 0; d < 64; ++d)
        Sl[tid][d] = (Qn[tid][d]-m2)*rs2*lnffg[d] + lnffb[d];
    }
    __syncthreads();
    if (tid < 896){
      const int s = tid >> 7, h = tid & 127;
      const float* f1 = fc1w + h*64;
      float acc2 = fc1b[h];
      #pragma unroll
      for (int d = 0; d < 64; ++d) acc2 += Sl[s][d]*f1[d];
      H1[s][h] = fmaxf(acc2, 0.f);
    }
    __syncthreads();
    if (tid < 448){
      const int s = tid >> 6, d = tid & 63;
      const float* f2 = fc2w + d*128;
      float o2 = fc2b[d];
      #pragma unroll
      for (int h = 0; h < 128; ++h) o2 += H1[s][h]*f2[h];
      float res = Qn[s][d] + o2;
      Sst[s][d] = res;
      if (it == 2 && party == 0) out[batch*448 + tid] = res;
    }
    __syncthreads();
  }
}

extern "C" void kernel_launch(void* const* d_in, const int* in_sizes, int n_in,
                              void* d_out, int out_size, void* d_ws, size_t ws_size,
                              hipStream_t stream)
{
  const float* inp   = (const float*)d_in[0];
  const float* noise = (const float*)d_in[1];
  const float* mu    = (const float*)d_in[2];
  const float* sigma = (const float*)d_in[3];
  const float* Wq    = (const float*)d_in[4];
  const float* Wk    = (const float*)d_in[5];
  const float* Wv    = (const float*)d_in[6];
  const float* gwih  = (const float*)d_in[7];
  const float* gwhh  = (const float*)d_in[8];
  const float* gbih  = (const float*)d_in[9];
  const float* gbhh  = (const float*)d_in[10];
  const float* fc1w  = (const float*)d_in[11];
  const float* fc1b  = (const float*)d_in[12];
  const float* fc2w  = (const float*)d_in[13];
  const float* fc2b  = (const float*)d_in[14];
  const float* lning = (const float*)d_in[15];
  const float* lninb = (const float*)d_in[16];
  const float* lnslg = (const float*)d_in[17];
  const float* lnslb = (const float*)d_in[18];
  const float* lnffg = (const float*)d_in[19];
  const float* lnffb = (const float*)d_in[20];
  const float* wiw   = (const float*)d_in[21];
  const float* wib   = (const float*)d_in[22];
  const float* wsw   = (const float*)d_in[23];
  const float* wsb   = (const float*)d_in[24];

  char* w = (char*)d_ws;
  u16*   knb     = (u16*)(w);                     // 33,554,432 B
  u16*   valb    = (u16*)(w + 33554432);          // 33,554,432 B
  float* lgA     = (float*)(w + 67108864);        // 1,048,576 B
  float* rnA     = (float*)(w + 68157440);        // 1,048,576 B
  float* lsePart = (float*)(w + 69206016);        // 2,048 B
  u64*   Tp      = (u64*)(w + 69208064);          // 2*128*8*8 = 16,384 B
  u64*   upT     = (u64*)(w + 69224448);          // 128*448*8 = 458,752 B
  // total ws usage ~= 66.4 MB

  k_zero<<<58, 1024, 0, stream>>>(Tp);
  k_pre<<<256, 1024, 0, stream>>>(inp, Wk, Wv, lning, lninb, wiw, wib,
                                  knb, valb, lgA, rnA, lsePart);
  k_mesh<<<128, 1024, 0, stream>>>(noise, mu, sigma, Wq,
                                   gwih, gwhh, gbih, gbhh,
                                   fc1w, fc1b, fc2w, fc2b,
                                   lnslg, lnslb, lnffg, lnffb, wsw, wsb,
                                   knb, valb, lgA, rnA, lsePart,
                                   Tp, upT, (float*)d_out);
  (void)in_sizes; (void)n_in; (void)out_size; (void)ws_size;
}